// Round 13
// baseline (57.226 us; speedup 1.0000x reference)
//
#include <hip/hip_runtime.h>
#include <hip/hip_cooperative_groups.h>

namespace cg = cooperative_groups;

// (B,C,H,W) = (8,19,512,512), fp32 everywhere.
constexpr int B_ = 8, C_ = 19, H_ = 512, W_ = 512;
constexpr int HW_ = H_ * W_;
constexpr int NB = 512;   // blocks (2/CU on 256 CUs)
constexpr int NT = 512;   // threads (8 waves)

// LDS (floats): [0..14336) work region; [14336..14848) A-table; [14848..14880) saw
constexpr int LDSF    = 14880;  // 59520 B -> 2 blocks/CU
constexpr int A_OFF   = 14336;
constexpr int SAW_OFF = 14848;
// eye-phase layout: xh 36x292 at 0; tile2 10x292 at 10512; wh 10x260 at 0
constexpr int XH_S = 292, T2_OFF = 10512, T2_S = 292, WH_S = 260;
// phase-B layout: whL 18x260 at 0; whR 18x260 at 4680; st 8x540 at 9360
constexpr int WHL_OFF = 0, WHR_OFF = 4680, ST_OFF = 9360, ST_S = 540;

// workspace offsets (floats):
constexpr long WS_BM   = 0;      // blockmax (z*32+ht), z = eye*8+b
constexpr long WS_EW   = 512;    // eyesumw
constexpr long WS_ESUM = 1024;   // esum (vb)
constexpr long WS_WH   = 4096;   // wh_g: 16 x 256 x 256 half-res eye fields
constexpr long WS_T3   = WS_WH + 16L * 256 * 256;  // t3: 8 x HW einsum field

__device__ __forceinline__ int refl(int i, int n) {
    i = (i < 0) ? -i : i;
    return (i >= n) ? (2 * n - 2 - i) : i;
}

// Distance-indexed normalized Gaussian weights in registers.
template<int ND>
__device__ __forceinline__ void gauss_reg(float (&wkr)[ND], float sigma) {
    float s = 0.f;
#pragma unroll
    for (int d = 0; d < ND; ++d) {
        const float t = d / sigma;
        wkr[d] = expf(-0.5f * t * t);
        s += (d ? 2.f : 1.f) * wkr[d];
    }
    const float inv = 1.f / s;
#pragma unroll
    for (int d = 0; d < ND; ++d) wkr[d] *= inv;
}

// Total-contribution weight of input position i under the K=21 reflect blur.
__device__ __forceinline__ float aweight(int i, const float (&wkr)[11]) {
    float a = 0.f;
#pragma unroll
    for (int t = 0; t < 21; ++t) {
        const float k = wkr[(t < 10) ? (10 - t) : (t - 10)];
        const int o = i + 10 - t;
        if (o >= 0 && o < H_) a += k;
        if (i >= 1 && i <= 10 && t <= 10 - i) a += k;
        if (i >= 501 && i <= 510 && t >= 521 - i) a += k;
    }
    return a;
}

// ========== Phase A part 1: HALF-RES eye pipeline ==========
// box2 downsample -> 27-tap H/W blur half-res (LDS) -> write HALF-RES field
// to wh_g -> upsample+mask only for the per-block max / A-weighted sum.
__device__ __forceinline__ void eye_tile(const float* __restrict__ mp,
                                         float* __restrict__ whg,
                                         float* __restrict__ blockmax,
                                         float* __restrict__ eyesumw,
                                         float* lds, int tid, int vb)
{
    float kh[14];
    gauss_reg(kh, 7.5f);                      // half-res sigma = 15/2
    const int b = vb >> 6, eye = (vb >> 5) & 1, ht = vb & 31;
    const int z = eye * 8 + b;
    const int i0 = ht * 8;                    // first half-row of this tile
    const float* sb = mp + ((long)b * C_ + 4 + eye) * HW_;

    __syncthreads();                          // work region free of prior use
    // ---- S1: box2 downsample into xh[36][292] (slot s = half-row i0-14+s)
    for (int t = 0; t < 10; ++t) {
        const int e = tid + t * NT;
        if (e < 36 * 142) {
            const int s = e / 142, p = e - s * 142;
            const int R = i0 - 14 + s;
            const long r0 = (long)refl(2 * R, H_) * W_;
            const long r1 = (long)refl(2 * R + 1, H_) * W_;
            const int fc = 4 * p - 28;
            float a0, a1;
            if (fc >= 0 && fc + 3 < W_) {
                const float4 u = *(const float4*)(sb + r0 + fc);
                const float4 v = *(const float4*)(sb + r1 + fc);
                a0 = (u.x + u.y + v.x + v.y) * 0.25f;
                a1 = (u.z + u.w + v.z + v.w) * 0.25f;
            } else {
                const int j0 = 2 * p - 14, j1 = j0 + 1;
                a0 = (sb[r0 + refl(2 * j0, W_)] + sb[r0 + refl(2 * j0 + 1, W_)]
                    + sb[r1 + refl(2 * j0, W_)] + sb[r1 + refl(2 * j0 + 1, W_)]) * 0.25f;
                a1 = (sb[r0 + refl(2 * j1, W_)] + sb[r0 + refl(2 * j1 + 1, W_)]
                    + sb[r1 + refl(2 * j1, W_)] + sb[r1 + refl(2 * j1 + 1, W_)]) * 0.25f;
            }
            *(float2*)(lds + s * XH_S + 2 * p) = make_float2(a0, a1);
        }
    }
    __syncthreads();
    // ---- S2: H-blur via register sliding window (thread = col slot, 10 outs)
    if (tid < 282) {
        float w2[36];
#pragma unroll
        for (int s = 0; s < 36; ++s) w2[s] = lds[s * XH_S + tid + 1];
#pragma unroll
        for (int r = 0; r < 10; ++r) {
            float a = 0.f;
#pragma unroll
            for (int dd = 0; dd < 27; ++dd)
                a = fmaf(w2[r + dd], kh[(dd < 13) ? (13 - dd) : (dd - 13)], a);
            lds[T2_OFF + r * T2_S + tid] = a;
        }
    }
    __syncthreads();
    // ---- S3: W-blur, b128 windows -> wh[10][260] LDS + owned rows -> wh_g
    {
        const int r = tid >> 6, g = tid & 63;
        {
            const float* trow = lds + T2_OFF + r * T2_S + 4 * g;
            float wn[32];
#pragma unroll
            for (int m = 0; m < 8; ++m) {
                const float4 v = *(const float4*)(trow + 4 * m);
                wn[4*m] = v.x; wn[4*m+1] = v.y; wn[4*m+2] = v.z; wn[4*m+3] = v.w;
            }
            float o4[4];
#pragma unroll
            for (int o = 0; o < 4; ++o) {
                float a = 0.f;
#pragma unroll
                for (int dd = 0; dd < 27; ++dd)
                    a = fmaf(wn[o + dd], kh[(dd < 13) ? (13 - dd) : (dd - 13)], a);
                o4[o] = a;
            }
            const float4 ov = make_float4(o4[0], o4[1], o4[2], o4[3]);
            *(float4*)(lds + r * WH_S + 4 * g) = ov;
            if (r >= 1)   // owned global half-row i0 + r - 1
                *(float4*)(whg + (long)z * 65536 + (long)(i0 + r - 1) * 256 + 4 * g) = ov;
        }
        if (tid < 128) {                      // rows 8,9
            const int r2 = 8 + (tid >> 6);
            const float* trow = lds + T2_OFF + r2 * T2_S + 4 * g;
            float wn[32];
#pragma unroll
            for (int m = 0; m < 8; ++m) {
                const float4 v = *(const float4*)(trow + 4 * m);
                wn[4*m] = v.x; wn[4*m+1] = v.y; wn[4*m+2] = v.z; wn[4*m+3] = v.w;
            }
            float o4[4];
#pragma unroll
            for (int o = 0; o < 4; ++o) {
                float a = 0.f;
#pragma unroll
                for (int dd = 0; dd < 27; ++dd)
                    a = fmaf(wn[o + dd], kh[(dd < 13) ? (13 - dd) : (dd - 13)], a);
                o4[o] = a;
            }
            const float4 ov = make_float4(o4[0], o4[1], o4[2], o4[3]);
            *(float4*)(lds + r2 * WH_S + 4 * g) = ov;
            if (r2 == 8)  // owned global half-row i0 + 7
                *(float4*)(whg + (long)z * 65536 + (long)(i0 + 7) * 256 + 4 * g) = ov;
        }
    }
    __syncthreads();
    // ---- S4: upsample + mask -> per-block max / A-weighted sum (NO write)
    const float* A = lds + A_OFF;
    const int c = tid;
    const int j = c >> 1;
    const int jn = (c & 1) ? ((j < 255) ? j + 1 : 255) : ((j > 0) ? j - 1 : 0);
    float cv[10];
#pragma unroll
    for (int s = 0; s < 10; ++s)
        cv[s] = 0.75f * lds[s * WH_S + j] + 0.25f * lds[s * WH_S + jn];
    const float Aw = A[c];
    const long mbase = (long)b * C_ * HW_ + (long)(ht * 16) * W_ + c;
    const float* eyp = mp + mbase + (long)(4 + eye) * HW_;
    const float* bgp = mp + mbase;
    float vmax = 0.f, vsum = 0.f;
#pragma unroll
    for (int o = 0; o < 16; ++o) {
        const int il = (o >> 1) + 1;
        const int i  = i0 + (o >> 1);
        const float cvn = (o & 1) ? ((i < 255) ? cv[il + 1] : cv[il])
                                  : ((i > 0)   ? cv[il - 1] : cv[il]);
        const float wv = 0.75f * cv[il] + 0.25f * cvn;
        const float ey = eyp[(long)o * W_], bg = bgp[(long)o * W_];
        const float v = wv * (1.f - ey) * (1.f - bg);
        vmax = fmaxf(vmax, v);
        vsum = fmaf(v, A[ht * 16 + o] * Aw, vsum);
    }
#pragma unroll
    for (int off = 32; off; off >>= 1) {
        vmax = fmaxf(vmax, __shfl_down(vmax, off));
        vsum += __shfl_down(vsum, off);
    }
    __syncthreads();
    if ((tid & 63) == 0) { lds[tid >> 6] = vmax; lds[8 + (tid >> 6)] = vsum; }
    __syncthreads();
    if (tid == 0) {
        float m = lds[0], s = lds[8];
        for (int i = 1; i < 8; ++i) { m = fmaxf(m, lds[i]); s += lds[8 + i]; }
        blockmax[z * 32 + ht] = m;
        eyesumw[z * 32 + ht] = s;
    }
}

// ========== Phase A part 2: einsum chunk + A-weighted sum ==================
__device__ __forceinline__ void einsum_part(const float* __restrict__ mp,
                                            float* __restrict__ t3,
                                            float* __restrict__ esum,
                                            float* lds, int tid, int vb)
{
    const float* A   = lds + A_OFF;
    const float* saw = lds + SAW_OFF;
    const int b = vb >> 6, chunk = vb & 63;
    float se = 0.f;
#pragma unroll
    for (int q = 0; q < 2; ++q) {
        const int p4 = chunk * 1024 + q * 512 + tid;
        const long p = (long)p4 * 4;
        const int h = (int)(p >> 9), w0 = (int)(p & 511);
        const float* mpb = mp + (long)b * C_ * HW_ + p;
        float4 acc = make_float4(0.f, 0.f, 0.f, 0.f);
#pragma unroll
        for (int c = 0; c < C_; ++c) {
            const float4 v = *(const float4*)(mpb + (long)c * HW_);
            const float a = saw[c];
            acc.x = fmaf(v.x, a, acc.x);
            acc.y = fmaf(v.y, a, acc.y);
            acc.z = fmaf(v.z, a, acc.z);
            acc.w = fmaf(v.w, a, acc.w);
        }
        *(float4*)(t3 + (long)b * HW_ + p) = acc;
        const float4 a4 = *(const float4*)(A + w0);
        se = fmaf(acc.x * a4.x + acc.y * a4.y + acc.z * a4.z + acc.w * a4.w,
                  A[h], se);
    }
#pragma unroll
    for (int off = 32; off; off >>= 1) se += __shfl_down(se, off);
    __syncthreads();
    if ((tid & 63) == 0) lds[tid >> 6] = se;
    __syncthreads();
    if (tid == 0) {
        float s = 0.f;
        for (int i = 0; i < 8; ++i) s += lds[i];
        esum[vb] = s;
    }
}

// ========== Phase B: recombine on-the-fly + 21-tap H+W blur + write ========
__device__ __forceinline__ void phaseB(const float* __restrict__ mp,
                                       const float* __restrict__ esw,
                                       const float* __restrict__ whg,
                                       const float* __restrict__ t3g,
                                       const float* __restrict__ blockmax,
                                       const float* __restrict__ eyesumw,
                                       const float* __restrict__ esum,
                                       float* __restrict__ out,
                                       float* lds, int tid, int vb)
{
    float wkr[11];
    gauss_reg(wkr, 2.f);
    const int b = vb >> 6, tile6 = vb & 63, hb = tile6 * 8;

    // uniform scalar reductions (identical in every thread)
    float mxL = blockmax[b * 32], mxR = blockmax[(8 + b) * 32];
    float SeL = 0.f, SeR = 0.f, Se = 0.f;
    for (int i = 0; i < 32; ++i) {
        mxL = fmaxf(mxL, blockmax[b * 32 + i]);
        mxR = fmaxf(mxR, blockmax[(8 + b) * 32 + i]);
        SeL += eyesumw[b * 32 + i];
        SeR += eyesumw[(8 + b) * 32 + i];
    }
    for (int i = 0; i < 64; ++i) Se += esum[b * 64 + i];
    const float e = esw[0];
    const float sl = e / mxL, sr = e / mxR;
    const float scale = (float)HW_ / (Se + sl * SeL + sr * SeR);

    // stage 18 half-rows of both eye fields into LDS
    int sb0 = ((hb - 10) >> 1) - 1;
    sb0 = sb0 < 0 ? 0 : (sb0 > 238 ? 238 : sb0);
    const float* whgL = whg + (long)b * 65536;
    const float* whgR = whg + (long)(8 + b) * 65536;
    float* whL = lds + WHL_OFF;   // [18][260]
    float* whR = lds + WHR_OFF;
    for (int e2 = tid; e2 < 18 * 64; e2 += NT) {
        const int r = e2 >> 6, g4 = e2 & 63;
        *(float4*)(whL + r * 260 + 4 * g4)
            = *(const float4*)(whgL + (long)(sb0 + r) * 256 + 4 * g4);
        *(float4*)(whR + r * 260 + 4 * g4)
            = *(const float4*)(whgR + (long)(sb0 + r) * 256 + 4 * g4);
    }
    __syncthreads();

    const float* mp0 = mp + (long)b * C_ * HW_;
    const float* t3b = t3g + (long)b * HW_;
    const int c = tid;
    const int j = c >> 1;
    const int jn = (c & 1) ? ((j < 255) ? j + 1 : 255) : ((j > 0) ? j - 1 : 0);

    // H-pass: streaming accumulate 28 recombined window rows into hv[8]
    float hv[8] = {0.f, 0.f, 0.f, 0.f, 0.f, 0.f, 0.f, 0.f};
#pragma unroll
    for (int i = 0; i < 28; ++i) {
        const int Rr = refl(hb - 10 + i, H_);
        const int irow = Rr >> 1;
        const int irn = (Rr & 1) ? ((irow < 255) ? irow + 1 : irow)
                                 : ((irow > 0) ? irow - 1 : irow);
        const int la = irow - sb0, lb = irn - sb0;
        const float cvLa = 0.75f * whL[la * 260 + j] + 0.25f * whL[la * 260 + jn];
        const float cvLb = 0.75f * whL[lb * 260 + j] + 0.25f * whL[lb * 260 + jn];
        const float wvL = 0.75f * cvLa + 0.25f * cvLb;
        const float cvRa = 0.75f * whR[la * 260 + j] + 0.25f * whR[la * 260 + jn];
        const float cvRb = 0.75f * whR[lb * 260 + j] + 0.25f * whR[lb * 260 + jn];
        const float wvR = 0.75f * cvRa + 0.25f * cvRb;
        const long po = (long)Rr * W_ + c;
        const float ch0 = mp0[po];
        const float ch4 = mp0[po + 4L * HW_];
        const float ch5 = mp0[po + 5L * HW_];
        const float vL = wvL * (1.f - ch4) * (1.f - ch0);
        const float vR = wvR * (1.f - ch5) * (1.f - ch0);
        const float win = fmaf(vL, sl, fmaf(vR, sr, t3b[po]));
#pragma unroll
        for (int j2 = 0; j2 < 8; ++j2) {
            const int k = i - j2;
            if (k >= 0 && k < 21)
                hv[j2] = fmaf(win, wkr[(k < 10) ? (10 - k) : (k - 10)], hv[j2]);
        }
    }
    float* st = lds + ST_OFF;                          // 8 x 540, col x at 12+x
#pragma unroll
    for (int j2 = 0; j2 < 8; ++j2) st[j2 * ST_S + 12 + c] = hv[j2];
    __syncthreads();
    if (tid < 224) {                                   // 8 rows x 28 halo cols
        const int r = tid / 28, q = tid - r * 28;
        float* srow = st + r * ST_S;
        if (q < 12) srow[11 - q] = srow[13 + q];
        else { const int cc = q - 12; srow[524 + cc] = srow[522 - cc]; }
    }
    __syncthreads();
    // W-pass: wave = row, lane = 8-col group; b128 window reads
    {
        const int r = tid >> 6, g = tid & 63, c0 = g * 8;
        const float* srow = st + r * ST_S;             // col x at srow[12+x]
        float wn[32];                                  // cols c0-12 .. c0+19
#pragma unroll
        for (int m = 0; m < 8; ++m) {
            const float4 v = *(const float4*)(srow + c0 + 4 * m);
            wn[4*m] = v.x; wn[4*m+1] = v.y; wn[4*m+2] = v.z; wn[4*m+3] = v.w;
        }
        float oo[8];
#pragma unroll
        for (int o = 0; o < 8; ++o) {
            float a = 0.f;
#pragma unroll
            for (int k = 0; k < 21; ++k)
                a = fmaf(wn[o + 2 + k], wkr[(k < 10) ? (10 - k) : (k - 10)], a);
            oo[o] = a * scale;
        }
        float* orow = out + (long)b * HW_ + (long)(hb + r) * W_ + c0;
        *(float4*)(orow)     = make_float4(oo[0], oo[1], oo[2], oo[3]);
        *(float4*)(orow + 4) = make_float4(oo[4], oo[5], oo[6], oo[7]);
    }
}

// ===================== cooperative mega kernel (1 grid.sync) ================
__global__ void __launch_bounds__(NT, 4)
mega_kern(const float* __restrict__ mp, const float* __restrict__ aw,
          const float* __restrict__ esw, float* __restrict__ out,
          float* __restrict__ ws)
{
    cg::grid_group grid = cg::this_grid();
    __shared__ __align__(16) float lds[LDSF];
    const int tid = threadIdx.x, bid = blockIdx.x;
    // XCD swizzle with vb>>6 = batch: all of batch b's work lands on XCD b.
    const int vb = (bid & 7) * 64 + (bid >> 3);
    float* blockmax = ws + WS_BM;
    float* eyesumw  = ws + WS_EW;
    float* esum     = ws + WS_ESUM;
    float* whg      = ws + WS_WH;
    float* t3       = ws + WS_T3;

    {   // A-weight table + area weights (above the work region)
        float w21[11];
        gauss_reg(w21, 2.f);
        lds[A_OFF + tid] = aweight(tid, w21);
    }
    if (tid < C_) lds[SAW_OFF + tid] = aw[tid];
    __syncthreads();

    // parity-alternated order: mixes compute-heavy and BW-heavy work chip-wide
    if (bid & 1) {
        einsum_part(mp, t3, esum, lds, tid, vb);
        eye_tile(mp, whg, blockmax, eyesumw, lds, tid, vb);
    } else {
        eye_tile(mp, whg, blockmax, eyesumw, lds, tid, vb);
        einsum_part(mp, t3, esum, lds, tid, vb);
    }
    grid.sync();
    phaseB(mp, esw, whg, t3, blockmax, eyesumw, esum, out, lds, tid, vb);
}

// ===================== fallback pipeline (2 kernels) =====================
__global__ void __launch_bounds__(NT)
fb_A_kern(const float* __restrict__ mp, const float* __restrict__ aw,
          float* __restrict__ ws)
{
    __shared__ __align__(16) float lds[LDSF];
    const int tid = threadIdx.x, bid = blockIdx.x;
    const int vb = (bid & 7) * 64 + (bid >> 3);
    float* blockmax = ws + WS_BM;
    float* eyesumw  = ws + WS_EW;
    float* esum     = ws + WS_ESUM;
    float* whg      = ws + WS_WH;
    float* t3       = ws + WS_T3;
    {
        float w21[11];
        gauss_reg(w21, 2.f);
        lds[A_OFF + tid] = aweight(tid, w21);
    }
    if (tid < C_) lds[SAW_OFF + tid] = aw[tid];
    __syncthreads();
    if (bid & 1) {
        einsum_part(mp, t3, esum, lds, tid, vb);
        eye_tile(mp, whg, blockmax, eyesumw, lds, tid, vb);
    } else {
        eye_tile(mp, whg, blockmax, eyesumw, lds, tid, vb);
        einsum_part(mp, t3, esum, lds, tid, vb);
    }
}

__global__ void __launch_bounds__(NT)
fb_B_kern(const float* __restrict__ mp, const float* __restrict__ esw,
          float* __restrict__ out, float* __restrict__ ws)
{
    __shared__ __align__(16) float lds[LDSF];
    const int tid = threadIdx.x, bid = blockIdx.x;
    const int vb = (bid & 7) * 64 + (bid >> 3);
    {   // phaseB needs no A-table, only wkr (registers); nothing to init
    }
    phaseB(mp, esw, ws + WS_WH, ws + WS_T3, ws + WS_BM, ws + WS_EW,
           ws + WS_ESUM, out, lds, tid, vb);
}

extern "C" void kernel_launch(void* const* d_in, const int* in_sizes, int n_in,
                              void* d_out, int out_size, void* d_ws, size_t ws_size,
                              hipStream_t stream)
{
    const float* mp  = (const float*)d_in[0];  // (8,19,512,512) f32
    const float* aw  = (const float*)d_in[1];  // (19,) f32
    const float* esw = (const float*)d_in[2];  // (1,) f32
    float* out = (float*)d_out;                // (8,1,512,512) f32
    float* wsf = (float*)d_ws;

    // Deterministic host-side decision (capture-safe: host queries only).
    int coop = 0, nb = 0;
    hipDeviceGetAttribute(&coop, hipDeviceAttributeCooperativeLaunch, 0);
    hipOccupancyMaxActiveBlocksPerMultiprocessor(&nb, (const void*)mega_kern, NT, 0);

    if (coop && nb >= 2) {
        void* args[] = { (void*)&mp, (void*)&aw, (void*)&esw, (void*)&out, (void*)&wsf };
        hipLaunchCooperativeKernel((void*)mega_kern, dim3(NB), dim3(NT), args, 0, stream);
    } else {
        fb_A_kern<<<NB, NT, 0, stream>>>(mp, aw, wsf);
        fb_B_kern<<<NB, NT, 0, stream>>>(mp, esw, out, wsf);
    }
}

// Round 14
// 53.571 us; speedup vs baseline: 1.0682x; 1.0682x over previous
//
#include <hip/hip_runtime.h>
#include <hip/hip_cooperative_groups.h>

namespace cg = cooperative_groups;

// (B,C,H,W) = (8,19,512,512), fp32 everywhere.
constexpr int B_ = 8, C_ = 19, H_ = 512, W_ = 512;
constexpr int HW_ = H_ * W_;
constexpr int NB = 512;   // blocks (2/CU on 256 CUs)
constexpr int NT = 512;   // threads (8 waves)
constexpr int QH = 128, QW = 128;   // quarter resolution

// LDS (floats): [0..14336) work region; [14336..14848) A-table; [14848..14880) saw
constexpr int LDSF    = 14880;  // 59520 B -> 2 blocks/CU
constexpr int A_OFF   = 14336;
constexpr int SAW_OFF = 14848;
// P1 eye layout: sgq 20x142 at 0; t2q 6x142 at 2944; whq 6x130 at 3840
constexpr int T2Q_OFF = 2944, WHQ_OFF = 3840;
// P2 layout: st 8x540 at 0
constexpr int ST_S = 540;

// workspace offsets (floats):
constexpr long WS_BM   = 0;      // blockmax (z*32+ht), z = eye*8+b
constexpr long WS_EW   = 512;    // eyesumw
constexpr long WS_ESUM = 1024;   // esum (vb)
constexpr long WS_DSG  = 4096;                    // dsg: 16 x 128 x 128
constexpr long WS_T0   = WS_DSG + 16L * QH * QW;  // t0: 24 images (w_l, w_r, t3)

__device__ __forceinline__ int refl(int i, int n) {
    i = (i < 0) ? -i : i;
    return (i >= n) ? (2 * n - 2 - i) : i;
}

// Distance-indexed normalized Gaussian weights in registers.
template<int ND>
__device__ __forceinline__ void gauss_reg(float (&wkr)[ND], float sigma) {
    float s = 0.f;
#pragma unroll
    for (int d = 0; d < ND; ++d) {
        const float t = d / sigma;
        wkr[d] = expf(-0.5f * t * t);
        s += (d ? 2.f : 1.f) * wkr[d];
    }
    const float inv = 1.f / s;
#pragma unroll
    for (int d = 0; d < ND; ++d) wkr[d] *= inv;
}

// Total-contribution weight of input position i under the K=21 reflect blur.
__device__ __forceinline__ float aweight(int i, const float (&wkr)[11]) {
    float a = 0.f;
#pragma unroll
    for (int t = 0; t < 21; ++t) {
        const float k = wkr[(t < 10) ? (10 - t) : (t - 10)];
        const int o = i + 10 - t;
        if (o >= 0 && o < H_) a += k;
        if (i >= 1 && i <= 10 && t <= 10 - i) a += k;
        if (i >= 501 && i <= 510 && t >= 521 - i) a += k;
    }
    return a;
}

// ========== Phase 0: box4 downsample of OWNED rows only (no halo) ==========
__device__ __forceinline__ void ds_tile(const float* __restrict__ mp,
                                        float* __restrict__ dsg, int tid, int vb)
{
    const int b = vb >> 6, eye = (vb >> 5) & 1, ht = vb & 31;
    const int z = eye * 8 + b;
    const float* sb = mp + ((long)b * C_ + 4 + eye) * HW_;
    const int q = tid >> 7, cg = tid & 127;
    const int fr = ht * 16 + q * 4;
    float s = 0.f;
#pragma unroll
    for (int r = 0; r < 4; ++r) {
        const float4 v = *(const float4*)(sb + (long)(fr + r) * W_ + 4 * cg);
        s += (v.x + v.y) + (v.z + v.w);
    }
    dsg[(long)z * (QH * QW) + (long)(ht * 4 + q) * QW + cg] = s * 0.0625f;
}

// ========== Phase 1a: quarter-res eye blur + upsample + mask + max/sum =====
__device__ __forceinline__ void eye_q(const float* __restrict__ mp,
                                      const float* __restrict__ dsg,
                                      float* __restrict__ t0,
                                      float* __restrict__ blockmax,
                                      float* __restrict__ eyesumw,
                                      float* lds, int tid, int vb)
{
    float kq[8];
    gauss_reg(kq, 3.75f);                     // quarter-res sigma = 15/4, K=15
    const int b = vb >> 6, eye = (vb >> 5) & 1, ht = vb & 31;
    const int z = eye * 8 + b;
    const float* dz = dsg + (long)z * (QH * QW);

    __syncthreads();                          // work region free of prior use
    // stage dsg rows [4ht-8, 4ht+12) with 7-col reflect halo -> sgq[20][142]
    float* sgq = lds;
    for (int t = 0; t < 6; ++t) {
        const int e = tid + t * NT;
        if (e < 20 * 142) {
            const int r = e / 142, c = e - r * 142;
            sgq[r * 142 + c] = dz[(long)refl(ht * 4 - 8 + r, QH) * QW + refl(c - 7, QW)];
        }
    }
    __syncthreads();
    // H-blur: 426 threads x 2 rows (register window 16) -> t2q[6][142]
    float* t2q = lds + T2Q_OFF;
    if (tid < 426) {
        const int g = tid / 142, c = tid - g * 142;
        float w[16];
#pragma unroll
        for (int s = 0; s < 16; ++s) w[s] = sgq[(2 * g + s) * 142 + c];
#pragma unroll
        for (int jr = 0; jr < 2; ++jr) {
            float a = 0.f;
#pragma unroll
            for (int d = 0; d < 15; ++d)
                a = fmaf(w[jr + d], kq[(d < 7) ? (7 - d) : (d - 7)], a);
            t2q[(2 * g + jr) * 142 + c] = a;
        }
    }
    __syncthreads();
    // W-blur -> whq[6][130] (quarter col j stored at +1; 0/129 replicated)
    float* whq = lds + WHQ_OFF;
#pragma unroll
    for (int t = 0; t < 2; ++t) {
        const int e = tid + t * NT;
        if (e < 768) {
            const int s = e >> 7, c = e & 127;
            float a = 0.f;
#pragma unroll
            for (int d = 0; d < 15; ++d)
                a = fmaf(t2q[s * 142 + c + d], kq[(d < 7) ? (7 - d) : (d - 7)], a);
            whq[s * 130 + c + 1] = a;
        }
    }
    __syncthreads();
    if (tid < 6) {
        whq[tid * 130]       = whq[tid * 130 + 1];
        whq[tid * 130 + 129] = whq[tid * 130 + 128];
    }
    __syncthreads();
    if (ht == 0 && tid < 130)  whq[tid]           = whq[130 + tid];
    if (ht == 31 && tid < 130) whq[5 * 130 + tid] = whq[4 * 130 + tid];
    __syncthreads();

    // S4: factor-4 bilinear upsample + mask + write v + per-block max/A-sum
    const float* A = lds + A_OFF;
    const int c = tid;
    const int j = ((c + 2) >> 2) - 1;         // -1..127 (stored at j+1: 0..128)
    const float fc = 0.625f + 0.25f * (float)(c & 1) - 0.5f * (float)((c >> 1) & 1);
    float cv[6];
#pragma unroll
    for (int s = 0; s < 6; ++s) {
        const float a0 = whq[s * 130 + j + 1], a1 = whq[s * 130 + j + 2];
        cv[s] = fmaf(fc, a1 - a0, a0);
    }
    const float Aw = A[c];
    const long mbase = (long)b * C_ * HW_ + (long)(ht * 16) * W_ + c;
    const float* eyp = mp + mbase + (long)(4 + eye) * HW_;
    const float* bgp = mp + mbase;
    float* db = t0 + (long)z * HW_ + (long)(ht * 16) * W_ + c;
    float vmax = 0.f, vsum = 0.f;
#pragma unroll
    for (int o = 0; o < 16; ++o) {
        const int ls0 = (o + 2) >> 2;         // static 0..4
        const float fr_ = 0.625f + 0.25f * (float)(o & 1) - 0.5f * (float)((o >> 1) & 1);
        const float wv = fmaf(fr_, cv[ls0 + 1] - cv[ls0], cv[ls0]);
        const float ey = eyp[(long)o * W_], bg = bgp[(long)o * W_];
        const float v = wv * (1.f - ey) * (1.f - bg);
        db[(long)o * W_] = v;
        vmax = fmaxf(vmax, v);
        vsum = fmaf(v, A[ht * 16 + o] * Aw, vsum);
    }
#pragma unroll
    for (int off = 32; off; off >>= 1) {
        vmax = fmaxf(vmax, __shfl_down(vmax, off));
        vsum += __shfl_down(vsum, off);
    }
    __syncthreads();                          // sgq/whq dead -> scratch ok
    if ((tid & 63) == 0) { lds[tid >> 6] = vmax; lds[8 + (tid >> 6)] = vsum; }
    __syncthreads();
    if (tid == 0) {
        float m = lds[0], s = lds[8];
        for (int i = 1; i < 8; ++i) { m = fmaxf(m, lds[i]); s += lds[8 + i]; }
        blockmax[z * 32 + ht] = m;
        eyesumw[z * 32 + ht] = s;
    }
}

// ========== Phase 1b: einsum chunk + A-weighted sum (R10 verbatim) =========
__device__ __forceinline__ void einsum_part(const float* __restrict__ mp,
                                            float* __restrict__ t3,
                                            float* __restrict__ esum,
                                            float* lds, int tid, int vb)
{
    const float* A   = lds + A_OFF;
    const float* saw = lds + SAW_OFF;
    const int b = vb >> 6, chunk = vb & 63;
    float se = 0.f;
#pragma unroll
    for (int q = 0; q < 2; ++q) {
        const int p4 = chunk * 1024 + q * 512 + tid;
        const long p = (long)p4 * 4;
        const int h = (int)(p >> 9), w0 = (int)(p & 511);
        const float* mpb = mp + (long)b * C_ * HW_ + p;
        float4 acc = make_float4(0.f, 0.f, 0.f, 0.f);
#pragma unroll
        for (int c = 0; c < C_; ++c) {
            const float4 v = *(const float4*)(mpb + (long)c * HW_);
            const float a = saw[c];
            acc.x = fmaf(v.x, a, acc.x);
            acc.y = fmaf(v.y, a, acc.y);
            acc.z = fmaf(v.z, a, acc.z);
            acc.w = fmaf(v.w, a, acc.w);
        }
        *(float4*)(t3 + (long)b * HW_ + p) = acc;
        const float4 a4 = *(const float4*)(A + w0);
        se = fmaf(acc.x * a4.x + acc.y * a4.y + acc.z * a4.z + acc.w * a4.w,
                  A[h], se);
    }
#pragma unroll
    for (int off = 32; off; off >>= 1) se += __shfl_down(se, off);
    __syncthreads();
    if ((tid & 63) == 0) lds[tid >> 6] = se;
    __syncthreads();
    if (tid == 0) {
        float s = 0.f;
        for (int i = 0; i < 8; ++i) s += lds[i];
        esum[vb] = s;
    }
}

// ========== Phase 2: combine + 21-tap blur, register windows (R10) =========
__device__ __forceinline__ void phaseB(const float* __restrict__ esw,
                                       const float* __restrict__ t0,
                                       const float* __restrict__ blockmax,
                                       const float* __restrict__ eyesumw,
                                       const float* __restrict__ esum,
                                       float* __restrict__ out,
                                       float* lds, int tid, int vb)
{
    float wkr[11];
    gauss_reg(wkr, 2.f);
    const int b = vb >> 6, tile6 = vb & 63, hb = tile6 * 8;

    // uniform scalar reductions (identical in every thread)
    float mxL = blockmax[b * 32], mxR = blockmax[(8 + b) * 32];
    float SeL = 0.f, SeR = 0.f, Se = 0.f;
    for (int i = 0; i < 32; ++i) {
        mxL = fmaxf(mxL, blockmax[b * 32 + i]);
        mxR = fmaxf(mxR, blockmax[(8 + b) * 32 + i]);
        SeL += eyesumw[b * 32 + i];
        SeR += eyesumw[(8 + b) * 32 + i];
    }
    for (int i = 0; i < 64; ++i) Se += esum[b * 64 + i];
    const float e = esw[0];
    const float sl = e / mxL, sr = e / mxR;
    const float scale = (float)HW_ / (Se + sl * SeL + sr * SeR);

    const float* t1 = t0 + (long)b * HW_;
    const float* t2 = t0 + (long)(8 + b) * HW_;
    const float* t3 = t0 + (long)(16 + b) * HW_;

    // H-pass: thread = col, combine + 28-row window straight from global
    const int c = tid;
    float win[28];
#pragma unroll
    for (int i = 0; i < 28; ++i) {
        const long off = (long)refl(hb - 10 + i, H_) * W_ + c;
        win[i] = fmaf(t1[off], sl, fmaf(t2[off], sr, t3[off]));
    }
    float hv[8];
#pragma unroll
    for (int j = 0; j < 8; ++j) {
        float a = 0.f;
#pragma unroll
        for (int k = 0; k < 21; ++k)
            a = fmaf(win[j + k], wkr[(k < 10) ? (10 - k) : (k - 10)], a);
        hv[j] = a;
    }
    __syncthreads();                                   // prior LDS use done
    float* st = lds;                                   // 8 x 540, col x at 12+x
#pragma unroll
    for (int j = 0; j < 8; ++j) st[j * ST_S + 12 + c] = hv[j];
    __syncthreads();
    if (tid < 224) {                                   // 8 rows x 28 halo cols
        const int r = tid / 28, q = tid - r * 28;
        float* srow = st + r * ST_S;
        if (q < 12) srow[11 - q] = srow[13 + q];
        else { const int cc = q - 12; srow[524 + cc] = srow[522 - cc]; }
    }
    __syncthreads();
    // W-pass: wave = row, lane = 8-col group; b128 window reads
    {
        const int r = tid >> 6, g = tid & 63, c0 = g * 8;
        const float* srow = st + r * ST_S;             // col x at srow[12+x]
        float wn[32];                                  // cols c0-12 .. c0+19
#pragma unroll
        for (int m = 0; m < 8; ++m) {
            const float4 v = *(const float4*)(srow + c0 + 4 * m);
            wn[4*m] = v.x; wn[4*m+1] = v.y; wn[4*m+2] = v.z; wn[4*m+3] = v.w;
        }
        float oo[8];
#pragma unroll
        for (int o = 0; o < 8; ++o) {
            float a = 0.f;
#pragma unroll
            for (int k = 0; k < 21; ++k)
                a = fmaf(wn[o + 2 + k], wkr[(k < 10) ? (10 - k) : (k - 10)], a);
            oo[o] = a * scale;
        }
        float* orow = out + (long)b * HW_ + (long)(hb + r) * W_ + c0;
        *(float4*)(orow)     = make_float4(oo[0], oo[1], oo[2], oo[3]);
        *(float4*)(orow + 4) = make_float4(oo[4], oo[5], oo[6], oo[7]);
    }
}

// ===================== cooperative mega kernel (2 grid.sync) ================
__global__ void __launch_bounds__(NT, 4)
mega_kern(const float* __restrict__ mp, const float* __restrict__ aw,
          const float* __restrict__ esw, float* __restrict__ out,
          float* __restrict__ ws)
{
    cg::grid_group grid = cg::this_grid();
    __shared__ __align__(16) float lds[LDSF];
    const int tid = threadIdx.x, bid = blockIdx.x;
    // XCD swizzle with vb>>6 = batch: all of batch b's work lands on XCD b.
    const int vb = (bid & 7) * 64 + (bid >> 3);
    float* blockmax = ws + WS_BM;
    float* eyesumw  = ws + WS_EW;
    float* esum     = ws + WS_ESUM;
    float* dsg      = ws + WS_DSG;
    float* t0       = ws + WS_T0;
    float* t3       = t0 + 16L * HW_;

    {   // A-weight table + area weights (above the work region)
        float w21[11];
        gauss_reg(w21, 2.f);
        lds[A_OFF + tid] = aweight(tid, w21);
    }
    if (tid < C_) lds[SAW_OFF + tid] = aw[tid];
    __syncthreads();

    // P0: dedup box4 downsample (owned rows only, tiny)
    ds_tile(mp, dsg, tid, vb);
    grid.sync();

    // P1: parity-alternated einsum + quarter-res eye pipeline
    if (bid & 1) {
        einsum_part(mp, t3, esum, lds, tid, vb);
        eye_q(mp, dsg, t0, blockmax, eyesumw, lds, tid, vb);
    } else {
        eye_q(mp, dsg, t0, blockmax, eyesumw, lds, tid, vb);
        einsum_part(mp, t3, esum, lds, tid, vb);
    }
    grid.sync();

    // P2: combine + final 21-tap blur + scaled write
    phaseB(esw, t0, blockmax, eyesumw, esum, out, lds, tid, vb);
}

// ===================== fallback pipeline (3 kernels) =====================
__global__ void __launch_bounds__(NT)
fb_P0_kern(const float* __restrict__ mp, float* __restrict__ ws)
{
    const int bid = blockIdx.x;
    const int vb = (bid & 7) * 64 + (bid >> 3);
    ds_tile(mp, ws + WS_DSG, threadIdx.x, vb);
}

__global__ void __launch_bounds__(NT)
fb_P1_kern(const float* __restrict__ mp, const float* __restrict__ aw,
           float* __restrict__ ws)
{
    __shared__ __align__(16) float lds[LDSF];
    const int tid = threadIdx.x, bid = blockIdx.x;
    const int vb = (bid & 7) * 64 + (bid >> 3);
    float* t0 = ws + WS_T0;
    {
        float w21[11];
        gauss_reg(w21, 2.f);
        lds[A_OFF + tid] = aweight(tid, w21);
    }
    if (tid < C_) lds[SAW_OFF + tid] = aw[tid];
    __syncthreads();
    if (bid & 1) {
        einsum_part(mp, t0 + 16L * HW_, ws + WS_ESUM, lds, tid, vb);
        eye_q(mp, ws + WS_DSG, t0, ws + WS_BM, ws + WS_EW, lds, tid, vb);
    } else {
        eye_q(mp, ws + WS_DSG, t0, ws + WS_BM, ws + WS_EW, lds, tid, vb);
        einsum_part(mp, t0 + 16L * HW_, ws + WS_ESUM, lds, tid, vb);
    }
}

__global__ void __launch_bounds__(NT)
fb_P2_kern(const float* __restrict__ esw, float* __restrict__ out,
           float* __restrict__ ws)
{
    __shared__ __align__(16) float lds[LDSF];
    const int tid = threadIdx.x, bid = blockIdx.x;
    const int vb = (bid & 7) * 64 + (bid >> 3);
    phaseB(esw, ws + WS_T0, ws + WS_BM, ws + WS_EW, ws + WS_ESUM,
           out, lds, tid, vb);
}

extern "C" void kernel_launch(void* const* d_in, const int* in_sizes, int n_in,
                              void* d_out, int out_size, void* d_ws, size_t ws_size,
                              hipStream_t stream)
{
    const float* mp  = (const float*)d_in[0];  // (8,19,512,512) f32
    const float* aw  = (const float*)d_in[1];  // (19,) f32
    const float* esw = (const float*)d_in[2];  // (1,) f32
    float* out = (float*)d_out;                // (8,1,512,512) f32
    float* wsf = (float*)d_ws;

    // Deterministic host-side decision (capture-safe: host queries only).
    int coop = 0, nb = 0;
    hipDeviceGetAttribute(&coop, hipDeviceAttributeCooperativeLaunch, 0);
    hipOccupancyMaxActiveBlocksPerMultiprocessor(&nb, (const void*)mega_kern, NT, 0);

    if (coop && nb >= 2) {
        void* args[] = { (void*)&mp, (void*)&aw, (void*)&esw, (void*)&out, (void*)&wsf };
        hipLaunchCooperativeKernel((void*)mega_kern, dim3(NB), dim3(NT), args, 0, stream);
    } else {
        fb_P0_kern<<<NB, NT, 0, stream>>>(mp, wsf);
        fb_P1_kern<<<NB, NT, 0, stream>>>(mp, aw, wsf);
        fb_P2_kern<<<NB, NT, 0, stream>>>(esw, out, wsf);
    }
}